// Round 7
// baseline (172.090 us; speedup 1.0000x reference)
//
#include <hip/hip_runtime.h>

#define CC 128
#define PAD 16            // one 64B line per atomic counter
typedef unsigned short ushort_t;
typedef unsigned int uint_t;
typedef __attribute__((ext_vector_type(8))) short short8_t;
typedef __attribute__((ext_vector_type(4))) float float4_t;

__device__ __forceinline__ ushort_t f2bf(float f) {
    uint_t u = __float_as_uint(f);
    u = (u + 0x7FFFu + ((u >> 16) & 1u)) >> 16;   // RNE
    return (ushort_t)u;
}

// ---------------- Kernel 0: pack W -> WbT[n][k] (bf16, transposed) ---------
__global__ void packw_kernel(const float* __restrict__ w, ushort_t* __restrict__ wbt) {
    const int i = blockIdx.x * 256 + threadIdx.x;
    if (i < CC * CC) {
        const int n = i >> 7, k = i & 127;
        wbt[i] = f2bf(w[k * CC + n]);
    }
}

// ---------------- Kernel 1: xw = x @ W via MFMA (split-precision A) --------
__global__ __launch_bounds__(256) void xw_kernel(const float* __restrict__ x,
                                                 const ushort_t* __restrict__ wbt,
                                                 ushort_t* __restrict__ xwb, int n) {
    const int wave = threadIdx.x >> 6;
    const int lane = threadIdx.x & 63;
    const int row0 = blockIdx.x * 64 + wave * 16;
    const int r  = lane & 15;        // A-row within tile / C-col
    const int kb = lane >> 4;        // k-block 0..3
    const int arow = row0 + r;
    const bool rok = arow < n;

    float4_t acc[8];
    #pragma unroll
    for (int t = 0; t < 8; ++t) acc[t] = (float4_t){0.f, 0.f, 0.f, 0.f};

    #pragma unroll
    for (int ks = 0; ks < 4; ++ks) {
        short8_t ahi, alo;
        if (rok) {
            const float* xp = &x[(size_t)arow * CC + ks * 32 + kb * 8];
            const float4 x0 = *reinterpret_cast<const float4*>(xp);
            const float4 x1 = *reinterpret_cast<const float4*>(xp + 4);
            const float xv[8] = {x0.x, x0.y, x0.z, x0.w, x1.x, x1.y, x1.z, x1.w};
            #pragma unroll
            for (int i = 0; i < 8; ++i) {
                const ushort_t h = f2bf(xv[i]);
                ahi[i] = (short)h;
                const float hf = __uint_as_float((uint_t)h << 16);
                alo[i] = (short)f2bf(xv[i] - hf);
            }
        } else {
            #pragma unroll
            for (int i = 0; i < 8; ++i) { ahi[i] = 0; alo[i] = 0; }
        }
        #pragma unroll
        for (int nt = 0; nt < 8; ++nt) {
            const short8_t b = *reinterpret_cast<const short8_t*>(
                &wbt[(size_t)(nt * 16 + r) * CC + ks * 32 + kb * 8]);
            acc[nt] = __builtin_amdgcn_mfma_f32_16x16x32_bf16(alo, b, acc[nt], 0, 0, 0);
            acc[nt] = __builtin_amdgcn_mfma_f32_16x16x32_bf16(ahi, b, acc[nt], 0, 0, 0);
        }
    }
    #pragma unroll
    for (int reg = 0; reg < 4; ++reg) {
        const int orow = row0 + kb * 4 + reg;
        if (orow < n) {
            #pragma unroll
            for (int nt = 0; nt < 8; ++nt)
                xwb[(size_t)orow * CC + nt * 16 + r] = f2bf(acc[nt][reg]);
        }
    }
}

// ---------------- Kernel 2: row & col histograms (padded counters) ---------
__global__ void hist_kernel(const int* __restrict__ ei, int* __restrict__ cnt_row,
                            int* __restrict__ cnt_col, int E) {
    int i = blockIdx.x * blockDim.x + threadIdx.x;
    int stride = gridDim.x * blockDim.x;
    for (; i < E; i += stride) {
        atomicAdd(&cnt_row[ei[i] * PAD], 1);
        atomicAdd(&cnt_col[ei[E + i] * PAD], 1);
    }
}

// ---------------- Kernel 3: blocksum + dinv + combo (fused) ----------------
__global__ void blocksum_kernel(const int* __restrict__ cnt_col, const int* __restrict__ cnt_row,
                                float* __restrict__ dinv, int* __restrict__ bsum,
                                const float* __restrict__ emb0, const float* __restrict__ emb1,
                                const float* __restrict__ emb2, float* __restrict__ combo, int n) {
    const int i = blockIdx.x * 256 + threadIdx.x;
    if (i < n) {
        int d = cnt_row[i * PAD];
        dinv[i] = (d > 0) ? rsqrtf((float)d) : 0.0f;
    }
    int v = (i < n) ? cnt_col[i * PAD] : 0;
    #pragma unroll
    for (int d = 32; d; d >>= 1) v += __shfl_down(v, d);
    __shared__ int wsum[4];
    if ((threadIdx.x & 63) == 0) wsum[threadIdx.x >> 6] = v;
    __syncthreads();
    if (threadIdx.x == 0) bsum[blockIdx.x] = wsum[0] + wsum[1] + wsum[2] + wsum[3];
    if (blockIdx.x < 60 && threadIdx.x < CC) {
        const int c = blockIdx.x, t = threadIdx.x;
        const int i0 = c / 12, j0 = (c % 12) / 2, k0 = c % 2;
        combo[c * CC + t] = emb0[i0 * CC + t] + emb1[j0 * CC + t] + emb2[k0 * CC + t];
    }
}

// ---------------- Kernels 4b/4c: scan of block sums, then offsets ----------
__global__ void bscan_kernel(const int* __restrict__ bsum, int* __restrict__ boff,
                             int nb, int* __restrict__ offs, int n) {
    __shared__ int tmp[256];
    const int t = threadIdx.x;
    int v = (t < nb) ? bsum[t] : 0;
    tmp[t] = v; __syncthreads();
    for (int d = 1; d < 256; d <<= 1) {
        int u = (t >= d) ? tmp[t - d] : 0; __syncthreads();
        tmp[t] += u; __syncthreads();
    }
    if (t < nb) boff[t] = tmp[t] - v;
    if (t == 255) offs[n] = tmp[255];
}

__global__ void offs_kernel(const int* __restrict__ cnt, const int* __restrict__ boff,
                            int* __restrict__ offs, int* __restrict__ next, int n) {
    __shared__ int tmp[256];
    const int t = threadIdx.x;
    const int i = blockIdx.x * 256 + t;
    int v = (i < n) ? cnt[i * PAD] : 0;
    tmp[t] = v; __syncthreads();
    for (int d = 1; d < 256; d <<= 1) {
        int u = (t >= d) ? tmp[t - d] : 0; __syncthreads();
        tmp[t] += u; __syncthreads();
    }
    if (i < n) {
        int e = boff[blockIdx.x] + tmp[t] - v;
        offs[i] = e;
        next[i * PAD] = e;
    }
}

// ---------------- Kernel 5: fill CSR records (padded cursors) --------------
// relies on n <= 65536 so row fits in 16 bits (n = 50000 here).
__global__ void fill_kernel(const int* __restrict__ ei, const int* __restrict__ ef,
                            const float* __restrict__ dinv, int* __restrict__ next,
                            int2* __restrict__ sc, int E) {
    int i = blockIdx.x * blockDim.x + threadIdx.x;
    int stride = gridDim.x * blockDim.x;
    for (; i < E; i += stride) {
        int r = ei[i];
        int c = ei[E + i];
        int pos = atomicAdd(&next[c * PAD], 1);
        int code = ef[i * 3 + 0] * 12 + ef[i * 3 + 1] * 2 + ef[i * 3 + 2];
        sc[pos] = make_int2(r | (code << 16), __float_as_int(dinv[r]));
    }
}

// ---------------- Kernel 6: gather — 1 wave per node, 2 edges in flight ----
__global__ void gather_kernel(const ushort_t* __restrict__ xwb, const int2* __restrict__ sc,
                              const int* __restrict__ offs, const float* __restrict__ dinv,
                              const float* __restrict__ combo, float* __restrict__ out, int n) {
    const int v = blockIdx.x * 4 + (threadIdx.x >> 6);
    if (v >= n) return;
    const int lane = threadIdx.x & 63;
    const int half = lane >> 5;
    const int l32 = lane & 31;
    const int end = offs[v + 1];

    float4 a0 = {0.f, 0.f, 0.f, 0.f}, a1 = {0.f, 0.f, 0.f, 0.f};

    #define GBODY(ACC, J)                                                                \
        {                                                                                \
            const int2 e_ = sc[J];                                                       \
            const int   r_ = e_.x & 0xFFFF, c_ = e_.x >> 16;                             \
            const float w_ = __int_as_float(e_.y);                                       \
            const uint2 u_ = *reinterpret_cast<const uint2*>(                            \
                &xwb[(size_t)r_ * CC + l32 * 4]);                                        \
            const float4 k_ = *reinterpret_cast<const float4*>(&combo[c_ * CC + l32 * 4]); \
            ACC.x += w_ * (__uint_as_float(u_.x << 16) + k_.x);                          \
            ACC.y += w_ * (__uint_as_float(u_.x & 0xFFFF0000u) + k_.y);                  \
            ACC.z += w_ * (__uint_as_float(u_.y << 16) + k_.z);                          \
            ACC.w += w_ * (__uint_as_float(u_.y & 0xFFFF0000u) + k_.w);                  \
        }

    int jj = offs[v] + half;
    for (; jj + 2 < end; jj += 4) { GBODY(a0, jj) GBODY(a1, jj + 2) }
    if (jj < end) GBODY(a0, jj)
    #undef GBODY

    a0.x += a1.x; a0.y += a1.y; a0.z += a1.z; a0.w += a1.w;
    a0.x += __shfl_xor(a0.x, 32);
    a0.y += __shfl_xor(a0.y, 32);
    a0.z += __shfl_xor(a0.z, 32);
    a0.w += __shfl_xor(a0.w, 32);

    if (half == 0) {
        const float s = dinv[v];
        *reinterpret_cast<float4*>(&out[(size_t)v * CC + l32 * 4]) =
            make_float4(s * a0.x, s * a0.y, s * a0.z, s * a0.w);
    }
}

extern "C" void kernel_launch(void* const* d_in, const int* in_sizes, int n_in,
                              void* d_out, int out_size, void* d_ws, size_t ws_size,
                              hipStream_t stream) {
    const float* x      = (const float*)d_in[0];
    const int*   ei     = (const int*)d_in[1];
    const int*   ef     = (const int*)d_in[2];
    const float* weight = (const float*)d_in[3];
    const float* emb0   = (const float*)d_in[4];
    const float* emb1   = (const float*)d_in[5];
    const float* emb2   = (const float*)d_in[6];
    float* out = (float*)d_out;

    const int n = in_sizes[0] / CC;        // 50000
    const int E = in_sizes[1] / 2;         // 625000
    const int nb = (n + 255) / 256;        // 196

    char* p = (char*)d_ws;
    auto alloc = [&](size_t bytes) {
        char* r = p;
        p += (bytes + 63) & ~(size_t)63;
        return r;
    };
    ushort_t* xwb   = (ushort_t*)alloc((size_t)n * CC * sizeof(ushort_t));
    ushort_t* wbt   = (ushort_t*)alloc(CC * CC * sizeof(ushort_t));
    float* combo    = (float*)alloc(60 * CC * sizeof(float));
    float* dinv     = (float*)alloc(n * sizeof(float));
    int*   cnt_row  = (int*)alloc((size_t)n * PAD * sizeof(int));
    int*   cnt_col  = (int*)alloc((size_t)n * PAD * sizeof(int));
    int*   next     = (int*)alloc((size_t)n * PAD * sizeof(int));
    int*   offs     = (int*)alloc((n + 1) * sizeof(int));
    int*   bsum     = (int*)alloc(nb * sizeof(int));
    int*   boff     = (int*)alloc(nb * sizeof(int));
    int2*  sc       = (int2*)alloc((size_t)E * sizeof(int2));

    hipMemsetAsync(cnt_row, 0, (size_t)n * PAD * sizeof(int), stream);
    hipMemsetAsync(cnt_col, 0, (size_t)n * PAD * sizeof(int), stream);

    // 0) pack W -> bf16 transposed
    packw_kernel<<<64, 256, 0, stream>>>(weight, wbt);
    // 1) xw = x @ W (MFMA, bf16 output)
    xw_kernel<<<(n + 63) / 64, 256, 0, stream>>>(x, wbt, xwb, n);
    // 2) histograms
    hist_kernel<<<2048, 256, 0, stream>>>(ei, cnt_row, cnt_col, E);
    // 3) blocksum + dinv + combo
    blocksum_kernel<<<nb, 256, 0, stream>>>(cnt_col, cnt_row, dinv, bsum,
                                            emb0, emb1, emb2, combo, n);
    // 4) scan
    bscan_kernel<<<1, 256, 0, stream>>>(bsum, boff, nb, offs, n);
    offs_kernel<<<nb, 256, 0, stream>>>(cnt_col, boff, offs, next, n);
    // 5) fill CSR records
    fill_kernel<<<2048, 256, 0, stream>>>(ei, ef, dinv, next, sc, E);
    // 6) gather
    gather_kernel<<<(n + 3) / 4, 256, 0, stream>>>(xwb, sc, offs, dinv, combo, out, n);
}

// Round 8
// 148.038 us; speedup vs baseline: 1.1625x; 1.1625x over previous
//
#include <hip/hip_runtime.h>

#define CC 128
#define NB_HIST 96        // histogram blocks (byte counters: per-chunk count must stay <256)
typedef unsigned short ushort_t;
typedef unsigned int uint_t;
typedef __attribute__((ext_vector_type(8))) short short8_t;
typedef __attribute__((ext_vector_type(4))) float float4_t;

__device__ __forceinline__ ushort_t f2bf(float f) {
    uint_t u = __float_as_uint(f);
    u = (u + 0x7FFFu + ((u >> 16) & 1u)) >> 16;   // RNE
    return (ushort_t)u;
}

// ---------------- Kernel 0: pack W -> WbT[n][k] (bf16, transposed) ---------
__global__ void packw_kernel(const float* __restrict__ w, ushort_t* __restrict__ wbt) {
    const int i = blockIdx.x * 256 + threadIdx.x;
    if (i < CC * CC) {
        const int n = i >> 7, k = i & 127;
        wbt[i] = f2bf(w[k * CC + n]);
    }
}

// ---------------- Kernel 1: xw = x @ W via MFMA (split-precision A) --------
__global__ __launch_bounds__(256) void xw_kernel(const float* __restrict__ x,
                                                 const ushort_t* __restrict__ wbt,
                                                 ushort_t* __restrict__ xwb, int n) {
    const int wave = threadIdx.x >> 6;
    const int lane = threadIdx.x & 63;
    const int row0 = blockIdx.x * 64 + wave * 16;
    const int r  = lane & 15;
    const int kb = lane >> 4;
    const int arow = row0 + r;
    const bool rok = arow < n;

    float4_t acc[8];
    #pragma unroll
    for (int t = 0; t < 8; ++t) acc[t] = (float4_t){0.f, 0.f, 0.f, 0.f};

    #pragma unroll
    for (int ks = 0; ks < 4; ++ks) {
        short8_t ahi, alo;
        if (rok) {
            const float* xp = &x[(size_t)arow * CC + ks * 32 + kb * 8];
            const float4 x0 = *reinterpret_cast<const float4*>(xp);
            const float4 x1 = *reinterpret_cast<const float4*>(xp + 4);
            const float xv[8] = {x0.x, x0.y, x0.z, x0.w, x1.x, x1.y, x1.z, x1.w};
            #pragma unroll
            for (int i = 0; i < 8; ++i) {
                const ushort_t h = f2bf(xv[i]);
                ahi[i] = (short)h;
                const float hf = __uint_as_float((uint_t)h << 16);
                alo[i] = (short)f2bf(xv[i] - hf);
            }
        } else {
            #pragma unroll
            for (int i = 0; i < 8; ++i) { ahi[i] = 0; alo[i] = 0; }
        }
        #pragma unroll
        for (int nt = 0; nt < 8; ++nt) {
            const short8_t b = *reinterpret_cast<const short8_t*>(
                &wbt[(size_t)(nt * 16 + r) * CC + ks * 32 + kb * 8]);
            acc[nt] = __builtin_amdgcn_mfma_f32_16x16x32_bf16(alo, b, acc[nt], 0, 0, 0);
            acc[nt] = __builtin_amdgcn_mfma_f32_16x16x32_bf16(ahi, b, acc[nt], 0, 0, 0);
        }
    }
    #pragma unroll
    for (int reg = 0; reg < 4; ++reg) {
        const int orow = row0 + kb * 4 + reg;
        if (orow < n) {
            #pragma unroll
            for (int nt = 0; nt < 8; ++nt)
                xwb[(size_t)orow * CC + nt * 16 + r] = f2bf(acc[nt][reg]);
        }
    }
}

// ---------------- Kernel 2a: LDS byte-histogram over one key array ---------
// Each block: contiguous edge chunk -> packed 8-bit counters in LDS (4/word),
// then dump 50KB local histogram to buf[block]. No global atomics.
__global__ __launch_bounds__(256) void hist_lds_kernel(const int* __restrict__ keys,
                                                       uint_t* __restrict__ buf,
                                                       int E, int nw) {
    __shared__ uint_t h[12512];              // supports n <= 50048
    const int tid = threadIdx.x;
    for (int i = tid; i < nw; i += 256) h[i] = 0u;
    __syncthreads();
    const int chunk = (E + NB_HIST - 1) / NB_HIST;
    const int beg = blockIdx.x * chunk;
    const int end = min(E, beg + chunk);
    for (int i = beg + tid; i < end; i += 256) {
        const int v = keys[i];
        atomicAdd(&h[v >> 2], 1u << ((v & 3) * 8));
    }
    __syncthreads();
    uint_t* ob = &buf[(size_t)blockIdx.x * nw];
    for (int i = tid; i < nw; i += 256) ob[i] = h[i];
}

// ---------------- Kernel 2b: reduce packed per-block histograms ------------
// Byte lanes never carry: each lane's total equals the node's final count (<256).
__global__ void hreduce_kernel(const uint_t* __restrict__ buf, int* __restrict__ dst,
                               int nw, int n) {
    const int w = blockIdx.x * 256 + threadIdx.x;
    if (w >= nw) return;
    uint_t s = 0;
    #pragma unroll 4
    for (int b = 0; b < NB_HIST; ++b) s += buf[(size_t)b * nw + w];
    const int base = w * 4;
    int4 o;
    o.x = (int)(s & 0xFFu);
    o.y = (int)((s >> 8) & 0xFFu);
    o.z = (int)((s >> 16) & 0xFFu);
    o.w = (int)(s >> 24);
    if (base + 3 < n) {
        *reinterpret_cast<int4*>(&dst[base]) = o;
    } else {
        if (base < n) dst[base] = o.x;
        if (base + 1 < n) dst[base + 1] = o.y;
        if (base + 2 < n) dst[base + 2] = o.z;
        if (base + 3 < n) dst[base + 3] = o.w;
    }
}

// ---------------- Kernel 2-fallback: global-atomic histograms --------------
__global__ void hist_kernel(const int* __restrict__ ei, int* __restrict__ cnt_row,
                            int* __restrict__ cnt_col, int E) {
    int i = blockIdx.x * blockDim.x + threadIdx.x;
    int stride = gridDim.x * blockDim.x;
    for (; i < E; i += stride) {
        atomicAdd(&cnt_row[ei[i]], 1);
        atomicAdd(&cnt_col[ei[E + i]], 1);
    }
}

// ---------------- Kernel 3: blocksum + dinv + combo (fused) ----------------
__global__ void blocksum_kernel(const int* __restrict__ cnt_col, const int* __restrict__ cnt_row,
                                float* __restrict__ dinv, int* __restrict__ bsum,
                                const float* __restrict__ emb0, const float* __restrict__ emb1,
                                const float* __restrict__ emb2, float* __restrict__ combo, int n) {
    const int i = blockIdx.x * 256 + threadIdx.x;
    if (i < n) {
        int d = cnt_row[i];
        dinv[i] = (d > 0) ? rsqrtf((float)d) : 0.0f;
    }
    int v = (i < n) ? cnt_col[i] : 0;
    #pragma unroll
    for (int d = 32; d; d >>= 1) v += __shfl_down(v, d);
    __shared__ int wsum[4];
    if ((threadIdx.x & 63) == 0) wsum[threadIdx.x >> 6] = v;
    __syncthreads();
    if (threadIdx.x == 0) bsum[blockIdx.x] = wsum[0] + wsum[1] + wsum[2] + wsum[3];
    if (blockIdx.x < 60 && threadIdx.x < CC) {
        const int c = blockIdx.x, t = threadIdx.x;
        const int i0 = c / 12, j0 = (c % 12) / 2, k0 = c % 2;
        combo[c * CC + t] = emb0[i0 * CC + t] + emb1[j0 * CC + t] + emb2[k0 * CC + t];
    }
}

// ---------------- Kernels 4b/4c: scan of block sums, then offsets ----------
__global__ void bscan_kernel(const int* __restrict__ bsum, int* __restrict__ boff,
                             int nb, int* __restrict__ offs, int n) {
    __shared__ int tmp[256];
    const int t = threadIdx.x;
    int v = (t < nb) ? bsum[t] : 0;
    tmp[t] = v; __syncthreads();
    for (int d = 1; d < 256; d <<= 1) {
        int u = (t >= d) ? tmp[t - d] : 0; __syncthreads();
        tmp[t] += u; __syncthreads();
    }
    if (t < nb) boff[t] = tmp[t] - v;
    if (t == 255) offs[n] = tmp[255];
}

__global__ void offs_kernel(const int* __restrict__ cnt, const int* __restrict__ boff,
                            int* __restrict__ offs, int* __restrict__ next, int n) {
    __shared__ int tmp[256];
    const int t = threadIdx.x;
    const int i = blockIdx.x * 256 + t;
    int v = (i < n) ? cnt[i] : 0;
    tmp[t] = v; __syncthreads();
    for (int d = 1; d < 256; d <<= 1) {
        int u = (t >= d) ? tmp[t - d] : 0; __syncthreads();
        tmp[t] += u; __syncthreads();
    }
    if (i < n) {
        int e = boff[blockIdx.x] + tmp[t] - v;
        offs[i] = e;
        next[i] = e;
    }
}

// ---------------- Kernel 5: fill CSR records (row|code packed, dinv_row) ---
// relies on n <= 65536 so row fits in 16 bits (n = 50000 here).
__global__ void fill_kernel(const int* __restrict__ ei, const int* __restrict__ ef,
                            const float* __restrict__ dinv, int* __restrict__ next,
                            int2* __restrict__ sc, int E) {
    int i = blockIdx.x * blockDim.x + threadIdx.x;
    int stride = gridDim.x * blockDim.x;
    for (; i < E; i += stride) {
        int r = ei[i];
        int c = ei[E + i];
        int pos = atomicAdd(&next[c], 1);
        int code = ef[i * 3 + 0] * 12 + ef[i * 3 + 1] * 2 + ef[i * 3 + 2];
        sc[pos] = make_int2(r | (code << 16), __float_as_int(dinv[r]));
    }
}

// ---------------- Kernel 6: gather — 1 wave per node, 2 edges in flight ----
__global__ void gather_kernel(const ushort_t* __restrict__ xwb, const int2* __restrict__ sc,
                              const int* __restrict__ offs, const float* __restrict__ dinv,
                              const float* __restrict__ combo, float* __restrict__ out, int n) {
    const int v = blockIdx.x * 4 + (threadIdx.x >> 6);
    if (v >= n) return;
    const int lane = threadIdx.x & 63;
    const int half = lane >> 5;
    const int l32 = lane & 31;
    const int end = offs[v + 1];

    float4 a0 = {0.f, 0.f, 0.f, 0.f}, a1 = {0.f, 0.f, 0.f, 0.f};

    #define GBODY(ACC, J)                                                                \
        {                                                                                \
            const int2 e_ = sc[J];                                                       \
            const int   r_ = e_.x & 0xFFFF, c_ = e_.x >> 16;                             \
            const float w_ = __int_as_float(e_.y);                                       \
            const uint2 u_ = *reinterpret_cast<const uint2*>(                            \
                &xwb[(size_t)r_ * CC + l32 * 4]);                                        \
            const float4 k_ = *reinterpret_cast<const float4*>(&combo[c_ * CC + l32 * 4]); \
            ACC.x += w_ * (__uint_as_float(u_.x << 16) + k_.x);                          \
            ACC.y += w_ * (__uint_as_float(u_.x & 0xFFFF0000u) + k_.y);                  \
            ACC.z += w_ * (__uint_as_float(u_.y << 16) + k_.z);                          \
            ACC.w += w_ * (__uint_as_float(u_.y & 0xFFFF0000u) + k_.w);                  \
        }

    int jj = offs[v] + half;
    for (; jj + 2 < end; jj += 4) { GBODY(a0, jj) GBODY(a1, jj + 2) }
    if (jj < end) GBODY(a0, jj)
    #undef GBODY

    a0.x += a1.x; a0.y += a1.y; a0.z += a1.z; a0.w += a1.w;
    a0.x += __shfl_xor(a0.x, 32);
    a0.y += __shfl_xor(a0.y, 32);
    a0.z += __shfl_xor(a0.z, 32);
    a0.w += __shfl_xor(a0.w, 32);

    if (half == 0) {
        const float s = dinv[v];
        *reinterpret_cast<float4*>(&out[(size_t)v * CC + l32 * 4]) =
            make_float4(s * a0.x, s * a0.y, s * a0.z, s * a0.w);
    }
}

extern "C" void kernel_launch(void* const* d_in, const int* in_sizes, int n_in,
                              void* d_out, int out_size, void* d_ws, size_t ws_size,
                              hipStream_t stream) {
    const float* x      = (const float*)d_in[0];
    const int*   ei     = (const int*)d_in[1];
    const int*   ef     = (const int*)d_in[2];
    const float* weight = (const float*)d_in[3];
    const float* emb0   = (const float*)d_in[4];
    const float* emb1   = (const float*)d_in[5];
    const float* emb2   = (const float*)d_in[6];
    float* out = (float*)d_out;

    const int n = in_sizes[0] / CC;        // 50000
    const int E = in_sizes[1] / 2;         // 625000
    const int nb = (n + 255) / 256;        // 196
    const int nw = (n + 3) / 4;            // packed words per histogram (12500)

    char* p = (char*)d_ws;
    auto alloc = [&](size_t bytes) {
        char* r = p;
        p += (bytes + 63) & ~(size_t)63;
        return r;
    };
    ushort_t* xwb   = (ushort_t*)alloc((size_t)n * CC * sizeof(ushort_t));
    ushort_t* wbt   = (ushort_t*)alloc(CC * CC * sizeof(ushort_t));
    float* combo    = (float*)alloc(60 * CC * sizeof(float));
    float* dinv     = (float*)alloc(n * sizeof(float));
    int*   cnt_row  = (int*)alloc((size_t)n * sizeof(int));
    int*   cnt_col  = (int*)alloc((size_t)n * sizeof(int));
    int*   offs     = (int*)alloc((n + 1) * sizeof(int));
    int*   next     = (int*)alloc((size_t)n * sizeof(int));
    int*   bsum     = (int*)alloc(nb * sizeof(int));
    int*   boff     = (int*)alloc(nb * sizeof(int));
    int2*  sc       = (int2*)alloc((size_t)E * sizeof(int2));
    uint_t* bufr    = (uint_t*)alloc((size_t)NB_HIST * nw * sizeof(uint_t));
    uint_t* bufc    = (uint_t*)alloc((size_t)NB_HIST * nw * sizeof(uint_t));

    // 0) pack W -> bf16 transposed
    packw_kernel<<<64, 256, 0, stream>>>(weight, wbt);
    // 1) xw = x @ W (MFMA, bf16 output)
    xw_kernel<<<(n + 63) / 64, 256, 0, stream>>>(x, wbt, xwb, n);
    // 2) histograms — LDS-privatized (no global atomics)
    if (n <= 50048) {
        hist_lds_kernel<<<NB_HIST, 256, 0, stream>>>(ei, bufr, E, nw);
        hist_lds_kernel<<<NB_HIST, 256, 0, stream>>>(ei + E, bufc, E, nw);
        hreduce_kernel<<<(nw + 255) / 256, 256, 0, stream>>>(bufr, cnt_row, nw, n);
        hreduce_kernel<<<(nw + 255) / 256, 256, 0, stream>>>(bufc, cnt_col, nw, n);
    } else {
        hipMemsetAsync(cnt_row, 0, (size_t)n * sizeof(int), stream);
        hipMemsetAsync(cnt_col, 0, (size_t)n * sizeof(int), stream);
        hist_kernel<<<2048, 256, 0, stream>>>(ei, cnt_row, cnt_col, E);
    }
    // 3) blocksum + dinv + combo
    blocksum_kernel<<<nb, 256, 0, stream>>>(cnt_col, cnt_row, dinv, bsum,
                                            emb0, emb1, emb2, combo, n);
    // 4) scan
    bscan_kernel<<<1, 256, 0, stream>>>(bsum, boff, nb, offs, n);
    offs_kernel<<<nb, 256, 0, stream>>>(cnt_col, boff, offs, next, n);
    // 5) fill CSR records
    fill_kernel<<<2048, 256, 0, stream>>>(ei, ef, dinv, next, sc, E);
    // 6) gather
    gather_kernel<<<(n + 3) / 4, 256, 0, stream>>>(xwb, sc, offs, dinv, combo, out, n);
}

// Round 9
// 120.556 us; speedup vs baseline: 1.4275x; 1.2280x over previous
//
#include <hip/hip_runtime.h>

#define CC 128
#define NB_HIST 96        // histogram/fill blocks; per-chunk per-node count must stay <256
#define MAXNW 12512       // LDS words: supports n <= 50048
typedef unsigned short ushort_t;
typedef unsigned int uint_t;
typedef __attribute__((ext_vector_type(8))) short short8_t;
typedef __attribute__((ext_vector_type(4))) float float4_t;

__device__ __forceinline__ ushort_t f2bf(float f) {
    uint_t u = __float_as_uint(f);
    u = (u + 0x7FFFu + ((u >> 16) & 1u)) >> 16;   // RNE
    return (ushort_t)u;
}
#define BF_LO(u) __uint_as_float((u) << 16)
#define BF_HI(u) __uint_as_float((u) & 0xFFFF0000u)

// ---------------- Kernel P: pack WbT (bf16,T) + combo table (bf16) ---------
__global__ void prep_kernel(const float* __restrict__ w, ushort_t* __restrict__ wbt,
                            const float* __restrict__ emb0, const float* __restrict__ emb1,
                            const float* __restrict__ emb2, ushort_t* __restrict__ cmb) {
    if (blockIdx.x < 64) {
        const int i = blockIdx.x * 256 + threadIdx.x;
        const int nn = i >> 7, k = i & 127;
        wbt[i] = f2bf(w[k * CC + nn]);
    } else {
        const int c = blockIdx.x - 64;        // 0..59
        const int t = threadIdx.x;
        if (c < 60 && t < CC) {
            const int i0 = c / 12, j0 = (c % 12) / 2, k0 = c % 2;
            cmb[c * CC + t] = f2bf(emb0[i0 * CC + t] + emb1[j0 * CC + t] + emb2[k0 * CC + t]);
        }
    }
}

// ---------------- Kernel 1: xw = x @ W via MFMA (split-precision A) --------
__global__ __launch_bounds__(256) void xw_kernel(const float* __restrict__ x,
                                                 const ushort_t* __restrict__ wbt,
                                                 ushort_t* __restrict__ xwb, int n) {
    const int wave = threadIdx.x >> 6;
    const int lane = threadIdx.x & 63;
    const int row0 = blockIdx.x * 64 + wave * 16;
    const int r  = lane & 15;
    const int kb = lane >> 4;
    const int arow = row0 + r;
    const bool rok = arow < n;

    float4_t acc[8];
    #pragma unroll
    for (int t = 0; t < 8; ++t) acc[t] = (float4_t){0.f, 0.f, 0.f, 0.f};

    #pragma unroll
    for (int ks = 0; ks < 4; ++ks) {
        short8_t ahi, alo;
        if (rok) {
            const float* xp = &x[(size_t)arow * CC + ks * 32 + kb * 8];
            const float4 x0 = *reinterpret_cast<const float4*>(xp);
            const float4 x1 = *reinterpret_cast<const float4*>(xp + 4);
            const float xv[8] = {x0.x, x0.y, x0.z, x0.w, x1.x, x1.y, x1.z, x1.w};
            #pragma unroll
            for (int i = 0; i < 8; ++i) {
                const ushort_t h = f2bf(xv[i]);
                ahi[i] = (short)h;
                const float hf = __uint_as_float((uint_t)h << 16);
                alo[i] = (short)f2bf(xv[i] - hf);
            }
        } else {
            #pragma unroll
            for (int i = 0; i < 8; ++i) { ahi[i] = 0; alo[i] = 0; }
        }
        #pragma unroll
        for (int nt = 0; nt < 8; ++nt) {
            const short8_t b = *reinterpret_cast<const short8_t*>(
                &wbt[(size_t)(nt * 16 + r) * CC + ks * 32 + kb * 8]);
            acc[nt] = __builtin_amdgcn_mfma_f32_16x16x32_bf16(alo, b, acc[nt], 0, 0, 0);
            acc[nt] = __builtin_amdgcn_mfma_f32_16x16x32_bf16(ahi, b, acc[nt], 0, 0, 0);
        }
    }
    #pragma unroll
    for (int reg = 0; reg < 4; ++reg) {
        const int orow = row0 + kb * 4 + reg;
        if (orow < n) {
            #pragma unroll
            for (int nt = 0; nt < 8; ++nt)
                xwb[(size_t)orow * CC + nt * 16 + r] = f2bf(acc[nt][reg]);
        }
    }
}

// ---------------- Kernel 2: both LDS byte-histograms in one pass -----------
__global__ __launch_bounds__(512) void hist2_kernel(const int* __restrict__ ei,
                                                    uint_t* __restrict__ bufr,
                                                    uint_t* __restrict__ bufc,
                                                    int E, int nw) {
    __shared__ uint_t hr[MAXNW];
    __shared__ uint_t hc[MAXNW];
    const int tid = threadIdx.x;
    for (int i = tid; i < nw; i += 512) { hr[i] = 0u; hc[i] = 0u; }
    __syncthreads();
    const int chunk = (E + NB_HIST - 1) / NB_HIST;
    const int beg = blockIdx.x * chunk;
    const int end = min(E, beg + chunk);
    for (int i = beg + tid; i < end; i += 512) {
        const int r = ei[i];
        const int c = ei[E + i];
        atomicAdd(&hr[r >> 2], 1u << ((r & 3) * 8));
        atomicAdd(&hc[c >> 2], 1u << ((c & 3) * 8));
    }
    __syncthreads();
    uint_t* obr = &bufr[(size_t)blockIdx.x * nw];
    uint_t* obc = &bufc[(size_t)blockIdx.x * nw];
    for (int i = tid; i < nw; i += 512) { obr[i] = hr[i]; obc[i] = hc[i]; }
}

// ---------------- Kernel 3: hscan — row: deg->dinv; col: scan+cnt+bsum -----
// grid = 2*nbw blocks of 256. Blocks [0,nbw): row reduce -> dinv.
// Blocks [nbw,2*nbw): col exclusive scan over NB_HIST (packed-byte, write
// back), per-word totals -> cnt_col, block total -> bsum[bid-nbw].
__global__ void hscan_kernel(uint_t* __restrict__ bufr, uint_t* __restrict__ bufc,
                             float* __restrict__ dinv, int* __restrict__ cnt_col,
                             int* __restrict__ bsum, int nbw, int nw, int n) {
    const int t = threadIdx.x;
    if ((int)blockIdx.x < nbw) {
        const int w = blockIdx.x * 256 + t;
        if (w >= nw) return;
        uint_t s = 0;
        #pragma unroll 4
        for (int b = 0; b < NB_HIST; ++b) s += bufr[(size_t)b * nw + w];
        const int base = w * 4;
        float4 o;
        o.x = (s & 0xFFu)         ? rsqrtf((float)(s & 0xFFu)) : 0.f;
        o.y = ((s >> 8) & 0xFFu)  ? rsqrtf((float)((s >> 8) & 0xFFu)) : 0.f;
        o.z = ((s >> 16) & 0xFFu) ? rsqrtf((float)((s >> 16) & 0xFFu)) : 0.f;
        o.w = (s >> 24)           ? rsqrtf((float)(s >> 24)) : 0.f;
        if (base + 3 < n) *reinterpret_cast<float4*>(&dinv[base]) = o;
        else {
            if (base < n) dinv[base] = o.x;
            if (base + 1 < n) dinv[base + 1] = o.y;
            if (base + 2 < n) dinv[base + 2] = o.z;
        }
    } else {
        const int w = (blockIdx.x - nbw) * 256 + t;
        int tot = 0;
        if (w < nw) {
            uint_t s = 0;
            for (int b = 0; b < NB_HIST; ++b) {
                const size_t idx = (size_t)b * nw + w;
                const uint_t u = bufc[idx];
                bufc[idx] = s;                 // exclusive prefix (packed bytes)
                s += u;
            }
            const int base = w * 4;
            int4 o;
            o.x = (int)(s & 0xFFu);
            o.y = (int)((s >> 8) & 0xFFu);
            o.z = (int)((s >> 16) & 0xFFu);
            o.w = (int)(s >> 24);
            if (base + 3 < n) { *reinterpret_cast<int4*>(&cnt_col[base]) = o; tot = o.x + o.y + o.z + o.w; }
            else {
                if (base < n) { cnt_col[base] = o.x; tot += o.x; }
                if (base + 1 < n) { cnt_col[base + 1] = o.y; tot += o.y; }
                if (base + 2 < n) { cnt_col[base + 2] = o.z; tot += o.z; }
            }
        }
        // block-reduce tot -> bsum
        #pragma unroll
        for (int d = 32; d; d >>= 1) tot += __shfl_down(tot, d);
        __shared__ int wsum[4];
        if ((t & 63) == 0) wsum[t >> 6] = tot;
        __syncthreads();
        if (t == 0) bsum[blockIdx.x - nbw] = wsum[0] + wsum[1] + wsum[2] + wsum[3];
    }
}

// ---------------- Kernel 4: scan of block sums ----------------
__global__ void bscan_kernel(const int* __restrict__ bsum, int* __restrict__ boff,
                             int nb, int* __restrict__ offs, int n) {
    __shared__ int tmp[256];
    const int t = threadIdx.x;
    int v = (t < nb) ? bsum[t] : 0;
    tmp[t] = v; __syncthreads();
    for (int d = 1; d < 256; d <<= 1) {
        int u = (t >= d) ? tmp[t - d] : 0; __syncthreads();
        tmp[t] += u; __syncthreads();
    }
    if (t < nb) boff[t] = tmp[t] - v;
    if (t == 255) offs[n] = tmp[255];
}

// ---------------- Kernel 5: offsets (1024 nodes / block) ----------------
__global__ void offs_kernel(const int* __restrict__ cnt, const int* __restrict__ boff,
                            int* __restrict__ offs, int* __restrict__ next, int nw, int n) {
    __shared__ int tmp[256];
    const int t = threadIdx.x;
    const int w = blockIdx.x * 256 + t;
    int4 c4 = {0, 0, 0, 0};
    const int base = w * 4;
    if (w < nw) {
        if (base + 3 < n) c4 = *reinterpret_cast<const int4*>(&cnt[base]);
        else {
            if (base < n) c4.x = cnt[base];
            if (base + 1 < n) c4.y = cnt[base + 1];
            if (base + 2 < n) c4.z = cnt[base + 2];
        }
    }
    const int tot = c4.x + c4.y + c4.z + c4.w;
    tmp[t] = tot; __syncthreads();
    for (int d = 1; d < 256; d <<= 1) {
        int u = (t >= d) ? tmp[t - d] : 0; __syncthreads();
        tmp[t] += u; __syncthreads();
    }
    if (w < nw) {
        int e = boff[blockIdx.x] + tmp[t] - tot;
        int4 o;
        o.x = e; o.y = e + c4.x; o.z = o.y + c4.y; o.w = o.z + c4.z;
        if (base + 3 < n) {
            *reinterpret_cast<int4*>(&offs[base]) = o;
            *reinterpret_cast<int4*>(&next[base]) = o;
        } else {
            if (base < n) { offs[base] = o.x; next[base] = o.x; }
            if (base + 1 < n) { offs[base + 1] = o.y; next[base + 1] = o.y; }
            if (base + 2 < n) { offs[base + 2] = o.z; next[base + 2] = o.z; }
        }
    }
}

// ---------------- Kernel 6: fill via LDS cursors (no global atomics) -------
// pos = offs[c] + cum_block(c) (scanned bufc bytes) + lds_rank.
__global__ __launch_bounds__(512) void fill_kernel(const int* __restrict__ ei,
                                                   const int* __restrict__ ef,
                                                   const float* __restrict__ dinv,
                                                   const uint_t* __restrict__ bufc,
                                                   const int* __restrict__ offs,
                                                   int2* __restrict__ sc, int E, int nw) {
    __shared__ uint_t cur[MAXNW];
    const int tid = threadIdx.x;
    for (int i = tid; i < nw; i += 512) cur[i] = 0u;
    __syncthreads();
    const int chunk = (E + NB_HIST - 1) / NB_HIST;
    const int beg = blockIdx.x * chunk;
    const int end = min(E, beg + chunk);
    const uint_t* myb = &bufc[(size_t)blockIdx.x * nw];
    for (int i = beg + tid; i < end; i += 512) {
        const int r = ei[i];
        const int c = ei[E + i];
        const int sh = (c & 3) * 8;
        const uint_t old = atomicAdd(&cur[c >> 2], 1u << sh);
        const int rank = (int)((old >> sh) & 0xFFu);
        const int cum = (int)((myb[c >> 2] >> sh) & 0xFFu);
        const int pos = offs[c] + cum + rank;
        const int code = ef[i * 3 + 0] * 12 + ef[i * 3 + 1] * 2 + ef[i * 3 + 2];
        sc[pos] = make_int2(r | (code << 16), __float_as_int(dinv[r]));
    }
}

// ---------------- Kernel 6-fallback: global-atomic fill --------------------
__global__ void fill_glob_kernel(const int* __restrict__ ei, const int* __restrict__ ef,
                                 const float* __restrict__ dinv, int* __restrict__ next,
                                 int2* __restrict__ sc, int E) {
    int i = blockIdx.x * blockDim.x + threadIdx.x;
    int stride = gridDim.x * blockDim.x;
    for (; i < E; i += stride) {
        int r = ei[i];
        int c = ei[E + i];
        int pos = atomicAdd(&next[c], 1);
        int code = ef[i * 3 + 0] * 12 + ef[i * 3 + 1] * 2 + ef[i * 3 + 2];
        sc[pos] = make_int2(r | (code << 16), __float_as_int(dinv[r]));
    }
}

// ---------------- fallback hist/dinv/blocksum (n > 50048) ------------------
__global__ void hist_kernel(const int* __restrict__ ei, int* __restrict__ cnt_row,
                            int* __restrict__ cnt_col, int E) {
    int i = blockIdx.x * blockDim.x + threadIdx.x;
    int stride = gridDim.x * blockDim.x;
    for (; i < E; i += stride) {
        atomicAdd(&cnt_row[ei[i]], 1);
        atomicAdd(&cnt_col[ei[E + i]], 1);
    }
}
__global__ void dinv_kernel(const int* __restrict__ cnt_row, float* __restrict__ dinv, int n) {
    int i = blockIdx.x * blockDim.x + threadIdx.x;
    if (i < n) {
        int d = cnt_row[i];
        dinv[i] = (d > 0) ? rsqrtf((float)d) : 0.0f;
    }
}
__global__ void blocksum2_kernel(const int* __restrict__ cnt, int* __restrict__ bsum,
                                 int nw, int n) {
    const int t = threadIdx.x;
    const int w = blockIdx.x * 256 + t;
    int tot = 0;
    const int base = w * 4;
    if (w < nw) {
        for (int k = 0; k < 4; ++k) if (base + k < n) tot += cnt[base + k];
    }
    #pragma unroll
    for (int d = 32; d; d >>= 1) tot += __shfl_down(tot, d);
    __shared__ int wsum[4];
    if ((t & 63) == 0) wsum[t >> 6] = tot;
    __syncthreads();
    if (t == 0) bsum[blockIdx.x] = wsum[0] + wsum[1] + wsum[2] + wsum[3];
}

// ---------------- Kernel 7: gather — 4 edges in flight, bf16 combo ---------
// lane = g*16 + l16; group g handles edge jj0+g; lane covers 8 channels.
__global__ void gather_kernel(const ushort_t* __restrict__ xwb, const int2* __restrict__ sc,
                              const int* __restrict__ offs, const float* __restrict__ dinv,
                              const ushort_t* __restrict__ cmb, float* __restrict__ out, int n) {
    const int v = blockIdx.x * 4 + (threadIdx.x >> 6);
    if (v >= n) return;
    const int lane = threadIdx.x & 63;
    const int g = lane >> 4;
    const int l16 = lane & 15;
    const int end = offs[v + 1];

    float a[8];
    #pragma unroll
    for (int k = 0; k < 8; ++k) a[k] = 0.f;

    int jj = offs[v] + g;
    int2 e = (jj < end) ? sc[jj] : make_int2(0, 0);   // w=0 contributes nothing
    while (jj < end) {
        const int2 en = (jj + 4 < end) ? sc[jj + 4] : make_int2(0, 0);
        const int r_ = e.x & 0xFFFF, c_ = e.x >> 16;
        const float w_ = __int_as_float(e.y);
        const uint4 ux = *reinterpret_cast<const uint4*>(&xwb[(size_t)r_ * CC + l16 * 8]);
        const uint4 uc = *reinterpret_cast<const uint4*>(&cmb[c_ * CC + l16 * 8]);
        a[0] += w_ * (BF_LO(ux.x) + BF_LO(uc.x));
        a[1] += w_ * (BF_HI(ux.x) + BF_HI(uc.x));
        a[2] += w_ * (BF_LO(ux.y) + BF_LO(uc.y));
        a[3] += w_ * (BF_HI(ux.y) + BF_HI(uc.y));
        a[4] += w_ * (BF_LO(ux.z) + BF_LO(uc.z));
        a[5] += w_ * (BF_HI(ux.z) + BF_HI(uc.z));
        a[6] += w_ * (BF_LO(ux.w) + BF_LO(uc.w));
        a[7] += w_ * (BF_HI(ux.w) + BF_HI(uc.w));
        e = en;
        jj += 4;
    }
    #pragma unroll
    for (int k = 0; k < 8; ++k) {
        a[k] += __shfl_xor(a[k], 16);
        a[k] += __shfl_xor(a[k], 32);
    }
    if (g == 0) {
        const float s = dinv[v];
        float4 o0 = make_float4(s * a[0], s * a[1], s * a[2], s * a[3]);
        float4 o1 = make_float4(s * a[4], s * a[5], s * a[6], s * a[7]);
        float* op = &out[(size_t)v * CC + l16 * 8];
        *reinterpret_cast<float4*>(op) = o0;
        *reinterpret_cast<float4*>(op + 4) = o1;
    }
}

extern "C" void kernel_launch(void* const* d_in, const int* in_sizes, int n_in,
                              void* d_out, int out_size, void* d_ws, size_t ws_size,
                              hipStream_t stream) {
    const float* x      = (const float*)d_in[0];
    const int*   ei     = (const int*)d_in[1];
    const int*   ef     = (const int*)d_in[2];
    const float* weight = (const float*)d_in[3];
    const float* emb0   = (const float*)d_in[4];
    const float* emb1   = (const float*)d_in[5];
    const float* emb2   = (const float*)d_in[6];
    float* out = (float*)d_out;

    const int n = in_sizes[0] / CC;        // 50000
    const int E = in_sizes[1] / 2;         // 625000
    const int nw = (n + 3) / 4;            // 12500
    const int nbw = (nw + 255) / 256;      // 49 (= blocks of 1024 nodes)

    char* p = (char*)d_ws;
    auto alloc = [&](size_t bytes) {
        char* r = p;
        p += (bytes + 63) & ~(size_t)63;
        return r;
    };
    ushort_t* xwb   = (ushort_t*)alloc((size_t)n * CC * sizeof(ushort_t));
    ushort_t* wbt   = (ushort_t*)alloc(CC * CC * sizeof(ushort_t));
    ushort_t* cmb   = (ushort_t*)alloc(60 * CC * sizeof(ushort_t));
    float* dinv     = (float*)alloc(n * sizeof(float));
    int*   cnt_row  = (int*)alloc((size_t)n * sizeof(int));
    int*   cnt_col  = (int*)alloc((size_t)n * sizeof(int));
    int*   offs     = (int*)alloc((n + 1) * sizeof(int));
    int*   next     = (int*)alloc((size_t)n * sizeof(int));
    int*   bsum     = (int*)alloc(nbw * sizeof(int));
    int*   boff     = (int*)alloc(nbw * sizeof(int));
    int2*  sc       = (int2*)alloc((size_t)E * sizeof(int2));
    uint_t* bufr    = (uint_t*)alloc((size_t)NB_HIST * nw * sizeof(uint_t));
    uint_t* bufc    = (uint_t*)alloc((size_t)NB_HIST * nw * sizeof(uint_t));

    // P) pack W (bf16,T) + combo (bf16)
    prep_kernel<<<124, 256, 0, stream>>>(weight, wbt, emb0, emb1, emb2, cmb);
    // 1) xw = x @ W (MFMA, bf16 output)
    xw_kernel<<<(n + 63) / 64, 256, 0, stream>>>(x, wbt, xwb, n);

    if (n <= 50048) {
        // 2) both histograms (LDS bytes, no global atomics)
        hist2_kernel<<<NB_HIST, 512, 0, stream>>>(ei, bufr, bufc, E, nw);
        // 3) row->dinv ; col->scan bufc + cnt_col + bsum
        hscan_kernel<<<2 * nbw, 256, 0, stream>>>(bufr, bufc, dinv, cnt_col, bsum, nbw, nw, n);
        // 4) scan block sums
        bscan_kernel<<<1, 256, 0, stream>>>(bsum, boff, nbw, offs, n);
        // 5) offsets
        offs_kernel<<<nbw, 256, 0, stream>>>(cnt_col, boff, offs, next, nw, n);
        // 6) fill via LDS cursors
        fill_kernel<<<NB_HIST, 512, 0, stream>>>(ei, ef, dinv, bufc, offs, sc, E, nw);
    } else {
        hipMemsetAsync(cnt_row, 0, (size_t)n * sizeof(int), stream);
        hipMemsetAsync(cnt_col, 0, (size_t)n * sizeof(int), stream);
        hist_kernel<<<2048, 256, 0, stream>>>(ei, cnt_row, cnt_col, E);
        dinv_kernel<<<(n + 255) / 256, 256, 0, stream>>>(cnt_row, dinv, n);
        blocksum2_kernel<<<nbw, 256, 0, stream>>>(cnt_col, bsum, nw, n);
        bscan_kernel<<<1, 256, 0, stream>>>(bsum, boff, nbw, offs, n);
        offs_kernel<<<nbw, 256, 0, stream>>>(cnt_col, boff, offs, next, nw, n);
        fill_glob_kernel<<<2048, 256, 0, stream>>>(ei, ef, dinv, next, sc, E);
    }
    // 7) gather
    gather_kernel<<<(n + 3) / 4, 256, 0, stream>>>(xwb, sc, offs, dinv, cmb, out, n);
}

// Round 10
// 114.487 us; speedup vs baseline: 1.5031x; 1.0530x over previous
//
#include <hip/hip_runtime.h>

#define CC 128
#define NB_HIST 96        // histogram/fill chunks; per-chunk per-node count must stay <256
#define MAXNW 12512       // LDS words: supports n <= 50048
typedef unsigned short ushort_t;
typedef unsigned int uint_t;
typedef __attribute__((ext_vector_type(8))) short short8_t;
typedef __attribute__((ext_vector_type(4))) float float4_t;

__device__ __forceinline__ ushort_t f2bf(float f) {
    uint_t u = __float_as_uint(f);
    u = (u + 0x7FFFu + ((u >> 16) & 1u)) >> 16;   // RNE
    return (ushort_t)u;
}
#define BF_LO(u) __uint_as_float((u) << 16)
#define BF_HI(u) __uint_as_float((u) & 0xFFFF0000u)

// ---------------- Kernel P: pack WbT (bf16,T) + combo table (bf16) ---------
__global__ void prep_kernel(const float* __restrict__ w, ushort_t* __restrict__ wbt,
                            const float* __restrict__ emb0, const float* __restrict__ emb1,
                            const float* __restrict__ emb2, ushort_t* __restrict__ cmb) {
    if (blockIdx.x < 64) {
        const int i = blockIdx.x * 256 + threadIdx.x;
        const int nn = i >> 7, k = i & 127;
        wbt[i] = f2bf(w[k * CC + nn]);
    } else {
        const int c = blockIdx.x - 64;        // 0..59
        const int t = threadIdx.x;
        if (c < 60 && t < CC) {
            const int i0 = c / 12, j0 = (c % 12) / 2, k0 = c % 2;
            cmb[c * CC + t] = f2bf(emb0[i0 * CC + t] + emb1[j0 * CC + t] + emb2[k0 * CC + t]);
        }
    }
}

// ---------------- Kernel 1: xw = x @ W via MFMA (split-precision A) --------
__global__ __launch_bounds__(256) void xw_kernel(const float* __restrict__ x,
                                                 const ushort_t* __restrict__ wbt,
                                                 ushort_t* __restrict__ xwb, int n) {
    const int wave = threadIdx.x >> 6;
    const int lane = threadIdx.x & 63;
    const int row0 = blockIdx.x * 64 + wave * 16;
    const int r  = lane & 15;
    const int kb = lane >> 4;
    const int arow = row0 + r;
    const bool rok = arow < n;

    float4_t acc[8];
    #pragma unroll
    for (int t = 0; t < 8; ++t) acc[t] = (float4_t){0.f, 0.f, 0.f, 0.f};

    #pragma unroll
    for (int ks = 0; ks < 4; ++ks) {
        short8_t ahi, alo;
        if (rok) {
            const float* xp = &x[(size_t)arow * CC + ks * 32 + kb * 8];
            const float4 x0 = *reinterpret_cast<const float4*>(xp);
            const float4 x1 = *reinterpret_cast<const float4*>(xp + 4);
            const float xv[8] = {x0.x, x0.y, x0.z, x0.w, x1.x, x1.y, x1.z, x1.w};
            #pragma unroll
            for (int i = 0; i < 8; ++i) {
                const ushort_t h = f2bf(xv[i]);
                ahi[i] = (short)h;
                const float hf = __uint_as_float((uint_t)h << 16);
                alo[i] = (short)f2bf(xv[i] - hf);
            }
        } else {
            #pragma unroll
            for (int i = 0; i < 8; ++i) { ahi[i] = 0; alo[i] = 0; }
        }
        #pragma unroll
        for (int nt = 0; nt < 8; ++nt) {
            const short8_t b = *reinterpret_cast<const short8_t*>(
                &wbt[(size_t)(nt * 16 + r) * CC + ks * 32 + kb * 8]);
            acc[nt] = __builtin_amdgcn_mfma_f32_16x16x32_bf16(alo, b, acc[nt], 0, 0, 0);
            acc[nt] = __builtin_amdgcn_mfma_f32_16x16x32_bf16(ahi, b, acc[nt], 0, 0, 0);
        }
    }
    #pragma unroll
    for (int reg = 0; reg < 4; ++reg) {
        const int orow = row0 + kb * 4 + reg;
        if (orow < n) {
            #pragma unroll
            for (int nt = 0; nt < 8; ++nt)
                xwb[(size_t)orow * CC + nt * 16 + r] = f2bf(acc[nt][reg]);
        }
    }
}

// ---------------- Kernel 2: both LDS byte-histograms in one pass -----------
// 1024 threads (16 waves) + 2-wide unroll for memory-level parallelism.
__global__ __launch_bounds__(1024) void hist2_kernel(const int* __restrict__ ei,
                                                     uint_t* __restrict__ bufr,
                                                     uint_t* __restrict__ bufc,
                                                     int E, int nw) {
    __shared__ uint_t hr[MAXNW];
    __shared__ uint_t hc[MAXNW];
    const int tid = threadIdx.x;
    for (int i = tid; i < nw; i += 1024) { hr[i] = 0u; hc[i] = 0u; }
    __syncthreads();
    const int chunk = (E + NB_HIST - 1) / NB_HIST;
    const int beg = blockIdx.x * chunk;
    const int end = min(E, beg + chunk);
    for (int i = beg + tid; i < end; i += 2048) {
        const int i1 = i + 1024;
        const bool ok1 = i1 < end;
        const int r0 = ei[i], c0 = ei[E + i];
        int r1 = 0, c1 = 0;
        if (ok1) { r1 = ei[i1]; c1 = ei[E + i1]; }
        atomicAdd(&hr[r0 >> 2], 1u << ((r0 & 3) * 8));
        atomicAdd(&hc[c0 >> 2], 1u << ((c0 & 3) * 8));
        if (ok1) {
            atomicAdd(&hr[r1 >> 2], 1u << ((r1 & 3) * 8));
            atomicAdd(&hc[c1 >> 2], 1u << ((c1 & 3) * 8));
        }
    }
    __syncthreads();
    uint_t* obr = &bufr[(size_t)blockIdx.x * nw];
    uint_t* obc = &bufc[(size_t)blockIdx.x * nw];
    for (int i = tid; i < nw; i += 1024) { obr[i] = hr[i]; obc[i] = hc[i]; }
}

// ---------------- Kernel 3: hscan — row: deg->dinv; col: scan+cnt+bsum -----
__global__ void hscan_kernel(uint_t* __restrict__ bufr, uint_t* __restrict__ bufc,
                             float* __restrict__ dinv, int* __restrict__ cnt_col,
                             int* __restrict__ bsum, int nbw, int nw, int n) {
    const int t = threadIdx.x;
    if ((int)blockIdx.x < nbw) {
        const int w = blockIdx.x * 256 + t;
        if (w >= nw) return;
        uint_t s = 0;
        #pragma unroll 4
        for (int b = 0; b < NB_HIST; ++b) s += bufr[(size_t)b * nw + w];
        const int base = w * 4;
        float4 o;
        o.x = (s & 0xFFu)         ? rsqrtf((float)(s & 0xFFu)) : 0.f;
        o.y = ((s >> 8) & 0xFFu)  ? rsqrtf((float)((s >> 8) & 0xFFu)) : 0.f;
        o.z = ((s >> 16) & 0xFFu) ? rsqrtf((float)((s >> 16) & 0xFFu)) : 0.f;
        o.w = (s >> 24)           ? rsqrtf((float)(s >> 24)) : 0.f;
        if (base + 3 < n) *reinterpret_cast<float4*>(&dinv[base]) = o;
        else {
            if (base < n) dinv[base] = o.x;
            if (base + 1 < n) dinv[base + 1] = o.y;
            if (base + 2 < n) dinv[base + 2] = o.z;
        }
    } else {
        const int w = (blockIdx.x - nbw) * 256 + t;
        int tot = 0;
        if (w < nw) {
            uint_t s = 0;
            for (int b = 0; b < NB_HIST; ++b) {
                const size_t idx = (size_t)b * nw + w;
                const uint_t u = bufc[idx];
                bufc[idx] = s;                 // exclusive prefix (packed bytes)
                s += u;
            }
            const int base = w * 4;
            int4 o;
            o.x = (int)(s & 0xFFu);
            o.y = (int)((s >> 8) & 0xFFu);
            o.z = (int)((s >> 16) & 0xFFu);
            o.w = (int)(s >> 24);
            if (base + 3 < n) { *reinterpret_cast<int4*>(&cnt_col[base]) = o; tot = o.x + o.y + o.z + o.w; }
            else {
                if (base < n) { cnt_col[base] = o.x; tot += o.x; }
                if (base + 1 < n) { cnt_col[base + 1] = o.y; tot += o.y; }
                if (base + 2 < n) { cnt_col[base + 2] = o.z; tot += o.z; }
            }
        }
        #pragma unroll
        for (int d = 32; d; d >>= 1) tot += __shfl_down(tot, d);
        __shared__ int wsum[4];
        if ((t & 63) == 0) wsum[t >> 6] = tot;
        __syncthreads();
        if (t == 0) bsum[blockIdx.x - nbw] = wsum[0] + wsum[1] + wsum[2] + wsum[3];
    }
}

// ---------------- Kernel 4: scan of block sums ----------------
__global__ void bscan_kernel(const int* __restrict__ bsum, int* __restrict__ boff,
                             int nb, int* __restrict__ offs, int n) {
    __shared__ int tmp[256];
    const int t = threadIdx.x;
    int v = (t < nb) ? bsum[t] : 0;
    tmp[t] = v; __syncthreads();
    for (int d = 1; d < 256; d <<= 1) {
        int u = (t >= d) ? tmp[t - d] : 0; __syncthreads();
        tmp[t] += u; __syncthreads();
    }
    if (t < nb) boff[t] = tmp[t] - v;
    if (t == 255) offs[n] = tmp[255];
}

// ---------------- Kernel 5: offsets (1024 nodes / block) ----------------
__global__ void offs_kernel(const int* __restrict__ cnt, const int* __restrict__ boff,
                            int* __restrict__ offs, int* __restrict__ next, int nw, int n) {
    __shared__ int tmp[256];
    const int t = threadIdx.x;
    const int w = blockIdx.x * 256 + t;
    int4 c4 = {0, 0, 0, 0};
    const int base = w * 4;
    if (w < nw) {
        if (base + 3 < n) c4 = *reinterpret_cast<const int4*>(&cnt[base]);
        else {
            if (base < n) c4.x = cnt[base];
            if (base + 1 < n) c4.y = cnt[base + 1];
            if (base + 2 < n) c4.z = cnt[base + 2];
        }
    }
    const int tot = c4.x + c4.y + c4.z + c4.w;
    tmp[t] = tot; __syncthreads();
    for (int d = 1; d < 256; d <<= 1) {
        int u = (t >= d) ? tmp[t - d] : 0; __syncthreads();
        tmp[t] += u; __syncthreads();
    }
    if (w < nw) {
        int e = boff[blockIdx.x] + tmp[t] - tot;
        int4 o;
        o.x = e; o.y = e + c4.x; o.z = o.y + c4.y; o.w = o.z + c4.z;
        if (base + 3 < n) {
            *reinterpret_cast<int4*>(&offs[base]) = o;
            *reinterpret_cast<int4*>(&next[base]) = o;
        } else {
            if (base < n) { offs[base] = o.x; next[base] = o.x; }
            if (base + 1 < n) { offs[base + 1] = o.y; next[base + 1] = o.y; }
            if (base + 2 < n) { offs[base + 2] = o.z; next[base + 2] = o.z; }
        }
    }
}

// ---------------- Kernel 6: fill via LDS cursors, 4-wide ILP ---------------
// pos = offs[c] + cum_block(c) (scanned bufc bytes) + lds_rank.
__global__ __launch_bounds__(1024) void fill_kernel(const int* __restrict__ ei,
                                                    const int* __restrict__ ef,
                                                    const float* __restrict__ dinv,
                                                    const uint_t* __restrict__ bufc,
                                                    const int* __restrict__ offs,
                                                    int2* __restrict__ sc, int E, int nw) {
    __shared__ uint_t cur[MAXNW];
    const int tid = threadIdx.x;
    for (int i = tid; i < nw; i += 1024) cur[i] = 0u;
    __syncthreads();
    const int chunk = (E + NB_HIST - 1) / NB_HIST;
    const int beg = blockIdx.x * chunk;
    const int end = min(E, beg + chunk);
    const uint_t* myb = &bufc[(size_t)blockIdx.x * nw];
    for (int i0 = beg + tid; i0 < end; i0 += 4096) {
        int  ii[4]; bool ok[4];
        int  r4[4], c4[4], code4[4], pos4[4];
        float dv4[4];
        #pragma unroll
        for (int u = 0; u < 4; ++u) { ii[u] = i0 + u * 1024; ok[u] = ii[u] < end; }
        #pragma unroll
        for (int u = 0; u < 4; ++u) if (ok[u]) { r4[u] = ei[ii[u]]; c4[u] = ei[E + ii[u]]; }
        #pragma unroll
        for (int u = 0; u < 4; ++u) if (ok[u])
            code4[u] = ef[ii[u] * 3 + 0] * 12 + ef[ii[u] * 3 + 1] * 2 + ef[ii[u] * 3 + 2];
        #pragma unroll
        for (int u = 0; u < 4; ++u) if (ok[u]) dv4[u] = dinv[r4[u]];
        #pragma unroll
        for (int u = 0; u < 4; ++u) if (ok[u]) {
            const int c = c4[u];
            const int sh = (c & 3) * 8;
            const uint_t old = atomicAdd(&cur[c >> 2], 1u << sh);
            const int rank = (int)((old >> sh) & 0xFFu);
            const int cum = (int)((myb[c >> 2] >> sh) & 0xFFu);
            pos4[u] = offs[c] + cum + rank;
        }
        #pragma unroll
        for (int u = 0; u < 4; ++u) if (ok[u])
            sc[pos4[u]] = make_int2(r4[u] | (code4[u] << 16), __float_as_int(dv4[u]));
    }
}

// ---------------- Kernel 6-fallback: global-atomic fill --------------------
__global__ void fill_glob_kernel(const int* __restrict__ ei, const int* __restrict__ ef,
                                 const float* __restrict__ dinv, int* __restrict__ next,
                                 int2* __restrict__ sc, int E) {
    int i = blockIdx.x * blockDim.x + threadIdx.x;
    int stride = gridDim.x * blockDim.x;
    for (; i < E; i += stride) {
        int r = ei[i];
        int c = ei[E + i];
        int pos = atomicAdd(&next[c], 1);
        int code = ef[i * 3 + 0] * 12 + ef[i * 3 + 1] * 2 + ef[i * 3 + 2];
        sc[pos] = make_int2(r | (code << 16), __float_as_int(dinv[r]));
    }
}

// ---------------- fallback hist/dinv/blocksum (n > 50048) ------------------
__global__ void hist_kernel(const int* __restrict__ ei, int* __restrict__ cnt_row,
                            int* __restrict__ cnt_col, int E) {
    int i = blockIdx.x * blockDim.x + threadIdx.x;
    int stride = gridDim.x * blockDim.x;
    for (; i < E; i += stride) {
        atomicAdd(&cnt_row[ei[i]], 1);
        atomicAdd(&cnt_col[ei[E + i]], 1);
    }
}
__global__ void dinv_kernel(const int* __restrict__ cnt_row, float* __restrict__ dinv, int n) {
    int i = blockIdx.x * blockDim.x + threadIdx.x;
    if (i < n) {
        int d = cnt_row[i];
        dinv[i] = (d > 0) ? rsqrtf((float)d) : 0.0f;
    }
}
__global__ void blocksum2_kernel(const int* __restrict__ cnt, int* __restrict__ bsum,
                                 int nw, int n) {
    const int t = threadIdx.x;
    const int w = blockIdx.x * 256 + t;
    int tot = 0;
    const int base = w * 4;
    if (w < nw) {
        for (int k = 0; k < 4; ++k) if (base + k < n) tot += cnt[base + k];
    }
    #pragma unroll
    for (int d = 32; d; d >>= 1) tot += __shfl_down(tot, d);
    __shared__ int wsum[4];
    if ((t & 63) == 0) wsum[t >> 6] = tot;
    __syncthreads();
    if (t == 0) bsum[blockIdx.x] = wsum[0] + wsum[1] + wsum[2] + wsum[3];
}

// ---------------- Kernel 7: gather — 4 edges in flight, bf16 combo ---------
__global__ void gather_kernel(const ushort_t* __restrict__ xwb, const int2* __restrict__ sc,
                              const int* __restrict__ offs, const float* __restrict__ dinv,
                              const ushort_t* __restrict__ cmb, float* __restrict__ out, int n) {
    const int v = blockIdx.x * 4 + (threadIdx.x >> 6);
    if (v >= n) return;
    const int lane = threadIdx.x & 63;
    const int g = lane >> 4;
    const int l16 = lane & 15;
    const int end = offs[v + 1];

    float a[8];
    #pragma unroll
    for (int k = 0; k < 8; ++k) a[k] = 0.f;

    int jj = offs[v] + g;
    int2 e = (jj < end) ? sc[jj] : make_int2(0, 0);   // w=0 contributes nothing
    while (jj < end) {
        const int2 en = (jj + 4 < end) ? sc[jj + 4] : make_int2(0, 0);
        const int r_ = e.x & 0xFFFF, c_ = e.x >> 16;
        const float w_ = __int_as_float(e.y);
        const uint4 ux = *reinterpret_cast<const uint4*>(&xwb[(size_t)r_ * CC + l16 * 8]);
        const uint4 uc = *reinterpret_cast<const uint4*>(&cmb[c_ * CC + l16 * 8]);
        a[0] += w_ * (BF_LO(ux.x) + BF_LO(uc.x));
        a[1] += w_ * (BF_HI(ux.x) + BF_HI(uc.x));
        a[2] += w_ * (BF_LO(ux.y) + BF_LO(uc.y));
        a[3] += w_ * (BF_HI(ux.y) + BF_HI(uc.y));
        a[4] += w_ * (BF_LO(ux.z) + BF_LO(uc.z));
        a[5] += w_ * (BF_HI(ux.z) + BF_HI(uc.z));
        a[6] += w_ * (BF_LO(ux.w) + BF_LO(uc.w));
        a[7] += w_ * (BF_HI(ux.w) + BF_HI(uc.w));
        e = en;
        jj += 4;
    }
    #pragma unroll
    for (int k = 0; k < 8; ++k) {
        a[k] += __shfl_xor(a[k], 16);
        a[k] += __shfl_xor(a[k], 32);
    }
    if (g == 0) {
        const float s = dinv[v];
        float4 o0 = make_float4(s * a[0], s * a[1], s * a[2], s * a[3]);
        float4 o1 = make_float4(s * a[4], s * a[5], s * a[6], s * a[7]);
        float* op = &out[(size_t)v * CC + l16 * 8];
        *reinterpret_cast<float4*>(op) = o0;
        *reinterpret_cast<float4*>(op + 4) = o1;
    }
}

extern "C" void kernel_launch(void* const* d_in, const int* in_sizes, int n_in,
                              void* d_out, int out_size, void* d_ws, size_t ws_size,
                              hipStream_t stream) {
    const float* x      = (const float*)d_in[0];
    const int*   ei     = (const int*)d_in[1];
    const int*   ef     = (const int*)d_in[2];
    const float* weight = (const float*)d_in[3];
    const float* emb0   = (const float*)d_in[4];
    const float* emb1   = (const float*)d_in[5];
    const float* emb2   = (const float*)d_in[6];
    float* out = (float*)d_out;

    const int n = in_sizes[0] / CC;        // 50000
    const int E = in_sizes[1] / 2;         // 625000
    const int nw = (n + 3) / 4;            // 12500
    const int nbw = (nw + 255) / 256;      // 49

    char* p = (char*)d_ws;
    auto alloc = [&](size_t bytes) {
        char* r = p;
        p += (bytes + 63) & ~(size_t)63;
        return r;
    };
    ushort_t* xwb   = (ushort_t*)alloc((size_t)n * CC * sizeof(ushort_t));
    ushort_t* wbt   = (ushort_t*)alloc(CC * CC * sizeof(ushort_t));
    ushort_t* cmb   = (ushort_t*)alloc(60 * CC * sizeof(ushort_t));
    float* dinv     = (float*)alloc(n * sizeof(float));
    int*   cnt_row  = (int*)alloc((size_t)n * sizeof(int));
    int*   cnt_col  = (int*)alloc((size_t)n * sizeof(int));
    int*   offs     = (int*)alloc((n + 1) * sizeof(int));
    int*   next     = (int*)alloc((size_t)n * sizeof(int));
    int*   bsum     = (int*)alloc(nbw * sizeof(int));
    int*   boff     = (int*)alloc(nbw * sizeof(int));
    int2*  sc       = (int2*)alloc((size_t)E * sizeof(int2));
    uint_t* bufr    = (uint_t*)alloc((size_t)NB_HIST * nw * sizeof(uint_t));
    uint_t* bufc    = (uint_t*)alloc((size_t)NB_HIST * nw * sizeof(uint_t));

    // P) pack W (bf16,T) + combo (bf16)
    prep_kernel<<<124, 256, 0, stream>>>(weight, wbt, emb0, emb1, emb2, cmb);
    // 1) xw = x @ W (MFMA, bf16 output)
    xw_kernel<<<(n + 63) / 64, 256, 0, stream>>>(x, wbt, xwb, n);

    if (n <= 50048) {
        // 2) both histograms (LDS bytes, no global atomics)
        hist2_kernel<<<NB_HIST, 1024, 0, stream>>>(ei, bufr, bufc, E, nw);
        // 3) row->dinv ; col->scan bufc + cnt_col + bsum
        hscan_kernel<<<2 * nbw, 256, 0, stream>>>(bufr, bufc, dinv, cnt_col, bsum, nbw, nw, n);
        // 4) scan block sums
        bscan_kernel<<<1, 256, 0, stream>>>(bsum, boff, nbw, offs, n);
        // 5) offsets
        offs_kernel<<<nbw, 256, 0, stream>>>(cnt_col, boff, offs, next, nw, n);
        // 6) fill via LDS cursors (4-wide ILP)
        fill_kernel<<<NB_HIST, 1024, 0, stream>>>(ei, ef, dinv, bufc, offs, sc, E, nw);
    } else {
        hipMemsetAsync(cnt_row, 0, (size_t)n * sizeof(int), stream);
        hipMemsetAsync(cnt_col, 0, (size_t)n * sizeof(int), stream);
        hist_kernel<<<2048, 256, 0, stream>>>(ei, cnt_row, cnt_col, E);
        dinv_kernel<<<(n + 255) / 256, 256, 0, stream>>>(cnt_row, dinv, n);
        blocksum2_kernel<<<nbw, 256, 0, stream>>>(cnt_col, bsum, nw, n);
        bscan_kernel<<<1, 256, 0, stream>>>(bsum, boff, nbw, offs, n);
        offs_kernel<<<nbw, 256, 0, stream>>>(cnt_col, boff, offs, next, nw, n);
        fill_glob_kernel<<<2048, 256, 0, stream>>>(ei, ef, dinv, next, sc, E);
    }
    // 7) gather
    gather_kernel<<<(n + 3) / 4, 256, 0, stream>>>(xwb, sc, offs, dinv, cmb, out, n);
}